// Round 3
// baseline (766.264 us; speedup 1.0000x reference)
//
#include <hip/hip_runtime.h>
#include <hip/hip_bf16.h>
#include <stdint.h>

#define N_NODES 50000
#define E_EDGES 400000
#define K1H 4
#define D_IN 1280
#define H_OUT 256
#define NTOT 1024          // K1H * H_OUT (fused GEMM output width)
#define MP 50176           // N padded to 196 row-tiles of 256
#define CAP 128            // edge bucket capacity per dest row (lambda=32, overflow ~e^-60)

typedef float f32x4 __attribute__((ext_vector_type(4)));
typedef short s16x8 __attribute__((ext_vector_type(8)));

#define GLOBAL_AS __attribute__((address_space(1)))
#define LDS_AS __attribute__((address_space(3)))

__device__ __forceinline__ void g2lds16(const void* g, void* l) {
    __builtin_amdgcn_global_load_lds((const GLOBAL_AS uint32_t*)g,
                                     (LDS_AS uint32_t*)l, 16, 0, 0);
}

// fp32 -> bf16 round-nearest-even
__device__ __forceinline__ ushort f2bf(float x) {
    uint32_t u = __float_as_uint(x);
    uint32_t r = u + 0x7FFFu + ((u >> 16) & 1u);
    return (ushort)(r >> 16);
}
__device__ __forceinline__ float bf2f(ushort u) {
    return __uint_as_float(((uint32_t)u) << 16);
}

// ---- Kernel 1a: X fp32 [N,D] -> Xb bf16 [MP,D], pad rows zeroed ----
__global__ void cvtX_kernel(const float* __restrict__ X, ushort* __restrict__ Xb) {
    int i = (blockIdx.x * 256 + threadIdx.x) * 4;   // MP*D_IN = 64,225,280 < 2^31
    ushort4 o;
    if (i < N_NODES * D_IN) {
        const float4 v = *(const float4*)(X + i);
        o.x = f2bf(v.x); o.y = f2bf(v.y); o.z = f2bf(v.z); o.w = f2bf(v.w);
    } else {
        o.x = 0; o.y = 0; o.z = 0; o.w = 0;
    }
    *(ushort4*)(Xb + i) = o;
}

// ---- Kernel 1b: W [4][1280][256] fp32 -> WbT bf16 [n=k*256+h][d] (B^T layout) ----
__global__ void cvtW_kernel(const float* __restrict__ W, ushort* __restrict__ WbT) {
    int o = blockIdx.x * 256 + threadIdx.x;
    if (o >= NTOT * D_IN) return;
    int n = o / D_IN, d = o - n * D_IN;
    int k = n >> 8, h = n & 255;
    WbT[o] = f2bf(W[(k * D_IN + d) * H_OUT + h]);
}

// ---- Kernel 2: single-pass bucket scatter.  edge record = (Yb offset, val) ----
__global__ void scatter_kernel(const int* __restrict__ rows, const int* __restrict__ cols,
                               const float* __restrict__ vals, int* __restrict__ cnt,
                               int2* __restrict__ edges) {
    int i = blockIdx.x * 256 + threadIdx.x;
    if (i >= K1H * E_EDGES) return;
    int k = i / E_EDGES;                     // hop index 0..3
    int r = rows[i];
    int pos = atomicAdd(&cnt[r], 1);
    if (pos < CAP)                           // statistically never taken
        edges[(size_t)r * CAP + pos] =
            make_int2((cols[i] << 10) | (k << 8), __float_as_int(vals[i]));
}

// ---- Kernel 3: GEMM  Yb[MP,1024] = Xb[MP,1280] @ WbT^T  (bf16 MFMA, bf16 out) ----
// 256x256 tile, BK=64, 8 waves (2Mx4N, 128x64 per wave), double-buffered LDS
// (128 KiB), counted vmcnt, and now FOUR phases per 2-K-tile iteration (was 8):
// each segment = {reads; stage; VMC; BARR; lgkm0; 2xMMA quadrant (32 MFMA)}.
// Halved convergence points -> longer segments for wave ILP to cover sync cost.
// Unit schedule (a=2i in buf0, b=2i+1 in buf1, a'=2i+2):
//   ph I : read a{Ag0,Bg0,Bg1}; stage b{Ag0,Bg0,Bg1}; VMC(6); MMA a Q00,Q01
//   ph II: read a{Ag1};         stage b{Ag1};         VMC(2); MMA a Q10,Q11
//   ph III:read b{Ag0,Bg0,Bg1}; stage a'{Ag0,Bg0,Bg1};VMC(6); MMA b Q00,Q01
//   ph IV: read b{Ag1};         stage a'{Ag1};        VMC(2); MMA b Q10,Q11
// Safety (verified): every stage(p) unit's last read is at segment p-2 (wave
// skew is bounded by 1 segment, so those reads completed via each wave's own
// lgkm0); stage(p) is unit-disjoint from reads(p) and in-flight reads(p-1)
// (Ag1 stages deferred to II/IV precisely because Ag1 reads are at II/IV);
// each VMC retires exactly the stages consumed after the following barrier
// (alternating 6,2 in gload-instruction counts; prologue drains with VMC(0)).
#define BARR() __builtin_amdgcn_s_barrier()
#define LGKM0() { asm volatile("s_waitcnt lgkmcnt(0)" ::: "memory"); \
                  __builtin_amdgcn_sched_barrier(0); }
#define VMC(N) asm volatile("s_waitcnt vmcnt(" #N ")" ::: "memory")

__global__ void __launch_bounds__(512, 2)
gemm_kernel(const ushort* __restrict__ Xb, const ushort* __restrict__ WbT,
            ushort* __restrict__ Yb) {
    __shared__ ushort lds[2][2][256 * 64];   // [dbuf][A=0,B=1][row*8+chunk], 128 KiB

    const int bid = blockIdx.x;               // 0 .. 783 (196 row-tiles x 4 col-tiles)
    const int xcd = bid & 7, j = bid >> 3;    // 98 blocks per XCD, contiguous tiles
    const int j2 = xcd * 98 + j;
    const int rt = j2 >> 2, ct = j2 & 3;
    const int rowBase = rt * 256, colBase = ct * 256;
    const int t = threadIdx.x;
    const int w = t >> 6, lane = t & 63;
    const int quad = lane >> 4, l16 = lane & 15;
    const int wm = w >> 2, wn = w & 3;        // 2 x 4 wave grid

    f32x4 acc[8][4] = {};
    s16x8 af[4][2];          // A frags, current mh half (reused across 2 quadrants)
    s16x8 bfr[2][2][2];      // B frags [nh][nt][ks], both halves held per tile

    const int kcg = (t & 7) ^ ((t >> 3) & 7);
    const ushort* pA = Xb + (rowBase + (t >> 3)) * D_IN + kcg * 8;
    const ushort* pB = WbT + (colBase + (t >> 3) + wm * 32) * D_IN + kcg * 8;

    // stage one 16KB half-tile (2 x global_load_lds per thread); LDS dst is
    // lane-linear (base + lane*16) as required by global_load_lds.
#define STAGE_A(BUF, G, KT) { _Pragma("unroll") \
    for (int r = 0; r < 2; ++r) \
        g2lds16(pA + (r * 128 + (G) * 64) * D_IN + (KT) * 64, \
                &lds[BUF][0][(t + (G) * 512 + r * 1024) * 8]); }
#define STAGE_B(BUF, G, KT) { _Pragma("unroll") \
    for (int r = 0; r < 2; ++r) \
        g2lds16(pB + (r * 128 + (G) * 32) * D_IN + (KT) * 64, \
                &lds[BUF][1][(t + wm * 256 + (G) * 256 + r * 1024) * 8]); }
#define LDA_F(BUF, MH) { _Pragma("unroll") \
    for (int mt = 0; mt < 4; ++mt) { \
        const int m = wm * 128 + (MH) * 64 + mt * 16 + l16; \
        _Pragma("unroll") for (int ks = 0; ks < 2; ++ks) \
            af[mt][ks] = *(const s16x8*)&lds[BUF][0][(m * 8 + ((ks * 4 + quad) ^ (l16 & 7))) * 8]; } }
#define LDB_F(BUF, NH) { _Pragma("unroll") \
    for (int nt = 0; nt < 2; ++nt) { \
        const int n = wn * 64 + (NH) * 32 + nt * 16 + l16; \
        _Pragma("unroll") for (int ks = 0; ks < 2; ++ks) \
            bfr[NH][nt][ks] = *(const s16x8*)&lds[BUF][1][(n * 8 + ((ks * 4 + quad) ^ (l16 & 7))) * 8]; } }
#define MMA_Q(MH, NH) { __builtin_amdgcn_s_setprio(1); \
    _Pragma("unroll") for (int mt = 0; mt < 4; ++mt) \
        _Pragma("unroll") for (int nt = 0; nt < 2; ++nt) \
            _Pragma("unroll") for (int ks = 0; ks < 2; ++ks) \
                acc[(MH) * 4 + mt][(NH) * 2 + nt] = \
                    __builtin_amdgcn_mfma_f32_16x16x32_bf16(af[mt][ks], bfr[NH][nt][ks], \
                        acc[(MH) * 4 + mt][(NH) * 2 + nt], 0, 0, 0); \
    __builtin_amdgcn_s_setprio(0); }

    // prologue: tile0 fully into buf0, drained; loop stages tile1+ naturally.
    STAGE_A(0, 0, 0); STAGE_B(0, 0, 0); STAGE_A(0, 1, 0); STAGE_B(0, 1, 0);
    VMC(0);
    BARR();

#pragma unroll 1
    for (int i = 0; i < 9; ++i) {
        const int kt0 = 2 * i;
        // phase I
        LDA_F(0, 0); LDB_F(0, 0); LDB_F(0, 1);
        STAGE_A(1, 0, kt0 + 1); STAGE_B(1, 0, kt0 + 1); STAGE_B(1, 1, kt0 + 1);
        VMC(6);
        BARR(); LGKM0(); MMA_Q(0, 0); MMA_Q(0, 1);
        // phase II
        LDA_F(0, 1);
        STAGE_A(1, 1, kt0 + 1);
        VMC(2);
        BARR(); LGKM0(); MMA_Q(1, 0); MMA_Q(1, 1);
        // phase III
        LDA_F(1, 0); LDB_F(1, 0); LDB_F(1, 1);
        STAGE_A(0, 0, kt0 + 2); STAGE_B(0, 0, kt0 + 2); STAGE_B(0, 1, kt0 + 2);
        VMC(6);
        BARR(); LGKM0(); MMA_Q(0, 0); MMA_Q(0, 1);
        // phase IV
        LDA_F(1, 1);
        STAGE_A(0, 1, kt0 + 2);
        VMC(2);
        BARR(); LGKM0(); MMA_Q(1, 0); MMA_Q(1, 1);
    }

    // tail iteration: tiles 18 (buf0) and 19 (buf1); only tile 19 still needs
    // staging (phases I,II); waits tighten since no further prefetch follows.
    LDA_F(0, 0); LDB_F(0, 0); LDB_F(0, 1);                             // I
    STAGE_A(1, 0, 19); STAGE_B(1, 0, 19); STAGE_B(1, 1, 19);
    VMC(6);
    BARR(); LGKM0(); MMA_Q(0, 0); MMA_Q(0, 1);
    LDA_F(0, 1);                                                       // II
    STAGE_A(1, 1, 19);
    VMC(2);
    BARR(); LGKM0(); MMA_Q(1, 0); MMA_Q(1, 1);
    LDA_F(1, 0); LDB_F(1, 0); LDB_F(1, 1);                             // III
    VMC(0);
    BARR(); LGKM0(); MMA_Q(0, 0); MMA_Q(0, 1);
    LDA_F(1, 1);                                                       // IV
    BARR(); LGKM0(); MMA_Q(1, 0); MMA_Q(1, 1);

    // C/D layout: col = lane&15, row = quad*4 + reg  (m89/m91 verified)
    #pragma unroll
    for (int mh = 0; mh < 2; ++mh)
      #pragma unroll
      for (int mt = 0; mt < 4; ++mt)
        #pragma unroll
        for (int nh = 0; nh < 2; ++nh)
          #pragma unroll
          for (int nt = 0; nt < 2; ++nt) {
            const int rr = rowBase + wm * 128 + mh * 64 + mt * 16 + quad * 4;
            const int cc = colBase + wn * 64 + nh * 32 + nt * 16 + l16;
            #pragma unroll
            for (int r = 0; r < 4; ++r)
                Yb[(rr + r) * NTOT + cc] = f2bf(acc[mh * 4 + mt][nh * 2 + nt][r]);
          }
}

#undef STAGE_A
#undef STAGE_B
#undef LDA_F
#undef LDB_F
#undef MMA_Q

// ---- Kernel 4: bucket gather-SpMM + bias + PReLU.  One WAVE per dest row ----
// Lane l holds h = l*4 .. l*4+3; per edge one coalesced 512B ushort4 slice load.
__global__ void __launch_bounds__(256)
spmm_kernel(const int2* __restrict__ edges, const int* __restrict__ cnt,
            const ushort* __restrict__ Yb, const float* __restrict__ b,
            const float* __restrict__ alpha, float* __restrict__ out) {
    const int wid = threadIdx.x >> 6, lane = threadIdx.x & 63;
    const int row = blockIdx.x * 4 + wid;          // N_NODES = 12500 * 4 exactly
    const int h0 = lane * 4;

    float4 acc = make_float4(0.f, 0.f, 0.f, 0.f);
    #pragma unroll
    for (int k = 0; k < K1H; ++k) {
        const float4 bb = *(const float4*)(b + k * H_OUT + h0);
        acc.x += bb.x; acc.y += bb.y; acc.z += bb.z; acc.w += bb.w;
    }

    const int2* eb = edges + (size_t)row * CAP;
    int e = cnt[row]; if (e > CAP) e = CAP;
    int j = 0;
    for (; j + 4 <= e; j += 4) {                   // 4 gather streams in flight
        const int2 e0 = eb[j], e1 = eb[j + 1], e2 = eb[j + 2], e3 = eb[j + 3];
        const ushort4 y0 = *(const ushort4*)(Yb + e0.x + h0);
        const ushort4 y1 = *(const ushort4*)(Yb + e1.x + h0);
        const ushort4 y2 = *(const ushort4*)(Yb + e2.x + h0);
        const ushort4 y3 = *(const ushort4*)(Yb + e3.x + h0);
        const float v0 = __int_as_float(e0.y), v1 = __int_as_float(e1.y);
        const float v2 = __int_as_float(e2.y), v3 = __int_as_float(e3.y);
        acc.x += v0 * bf2f(y0.x) + v1 * bf2f(y1.x) + v2 * bf2f(y2.x) + v3 * bf2f(y3.x);
        acc.y += v0 * bf2f(y0.y) + v1 * bf2f(y1.y) + v2 * bf2f(y2.y) + v3 * bf2f(y3.y);
        acc.z += v0 * bf2f(y0.z) + v1 * bf2f(y1.z) + v2 * bf2f(y2.z) + v3 * bf2f(y3.z);
        acc.w += v0 * bf2f(y0.w) + v1 * bf2f(y1.w) + v2 * bf2f(y2.w) + v3 * bf2f(y3.w);
    }
    for (; j < e; ++j) {
        const int2 ed = eb[j];
        const float v = __int_as_float(ed.y);
        const ushort4 y = *(const ushort4*)(Yb + ed.x + h0);
        acc.x += v * bf2f(y.x);
        acc.y += v * bf2f(y.y);
        acc.z += v * bf2f(y.z);
        acc.w += v * bf2f(y.w);
    }

    const float a = alpha[0];
    float4 o;
    o.x = acc.x >= 0.f ? acc.x : a * acc.x;
    o.y = acc.y >= 0.f ? acc.y : a * acc.y;
    o.z = acc.z >= 0.f ? acc.z : a * acc.z;
    o.w = acc.w >= 0.f ? acc.w : a * acc.w;
    *(float4*)(out + row * H_OUT + h0) = o;
}

static inline size_t align256(size_t x) { return (x + 255) & ~(size_t)255; }

extern "C" void kernel_launch(void* const* d_in, const int* in_sizes, int n_in,
                              void* d_out, int out_size, void* d_ws, size_t ws_size,
                              hipStream_t stream) {
    const float* X     = (const float*)d_in[0];
    const int*   rows  = (const int*)d_in[1];
    const int*   cols  = (const int*)d_in[2];
    const float* vals  = (const float*)d_in[3];
    const float* W     = (const float*)d_in[4];
    const float* b     = (const float*)d_in[5];
    const float* alpha = (const float*)d_in[6];
    float* out = (float*)d_out;

    char* ws = (char*)d_ws;
    size_t off = 0;
    ushort* Xb  = (ushort*)(ws + off); off = align256(off + (size_t)MP * D_IN * 2);
    ushort* WbT = (ushort*)(ws + off); off = align256(off + (size_t)NTOT * D_IN * 2);
    ushort* Yb  = (ushort*)(ws + off); off = align256(off + (size_t)MP * NTOT * 2);
    int* cnt    = (int*)(ws + off);    off = align256(off + (size_t)N_NODES * 4);
    int2* edges = (int2*)(ws + off);   off = align256(off + (size_t)N_NODES * CAP * 8);

    hipMemsetAsync(cnt, 0, (size_t)N_NODES * 4, stream);

    cvtX_kernel<<<MP * D_IN / 4 / 256, 256, 0, stream>>>(X, Xb);
    cvtW_kernel<<<(NTOT * D_IN + 255) / 256, 256, 0, stream>>>(W, WbT);
    scatter_kernel<<<(K1H * E_EDGES + 255) / 256, 256, 0, stream>>>(rows, cols, vals, cnt, edges);
    gemm_kernel<<<196 * 4, 512, 0, stream>>>(Xb, WbT, Yb);
    spmm_kernel<<<N_NODES / 4, 256, 0, stream>>>(edges, cnt, Yb, b, alpha, out);
}

// Round 4
// 734.525 us; speedup vs baseline: 1.0432x; 1.0432x over previous
//
#include <hip/hip_runtime.h>
#include <hip/hip_bf16.h>
#include <stdint.h>

#define N_NODES 50000
#define E_EDGES 400000
#define K1H 4
#define D_IN 1280
#define H_OUT 256
#define NTOT 1024          // K1H * H_OUT (fused GEMM output width)
#define MP 50176           // N padded: 176 row-tiles of 256 + 40 row-tiles of 128
#define NFULL 704          // 176 full row-tiles * 4 col-tiles
#define NHALF 160          // 40 half row-tiles * 4 col-tiles
#define HALF_BASE 45056    // first row of the half-tile region (176*256)
#define CAP 128            // edge bucket capacity per dest row (lambda=32, overflow ~e^-60)

typedef float f32x4 __attribute__((ext_vector_type(4)));
typedef short s16x8 __attribute__((ext_vector_type(8)));

#define GLOBAL_AS __attribute__((address_space(1)))
#define LDS_AS __attribute__((address_space(3)))

__device__ __forceinline__ void g2lds16(const void* g, void* l) {
    __builtin_amdgcn_global_load_lds((const GLOBAL_AS uint32_t*)g,
                                     (LDS_AS uint32_t*)l, 16, 0, 0);
}

// fp32 -> bf16 round-nearest-even
__device__ __forceinline__ ushort f2bf(float x) {
    uint32_t u = __float_as_uint(x);
    uint32_t r = u + 0x7FFFu + ((u >> 16) & 1u);
    return (ushort)(r >> 16);
}
__device__ __forceinline__ float bf2f(ushort u) {
    return __uint_as_float(((uint32_t)u) << 16);
}

// ---- Kernel 1a: X fp32 [N,D] -> Xb bf16 [MP,D], pad rows zeroed ----
__global__ void cvtX_kernel(const float* __restrict__ X, ushort* __restrict__ Xb) {
    int i = (blockIdx.x * 256 + threadIdx.x) * 4;   // MP*D_IN = 64,225,280 < 2^31
    ushort4 o;
    if (i < N_NODES * D_IN) {
        const float4 v = *(const float4*)(X + i);
        o.x = f2bf(v.x); o.y = f2bf(v.y); o.z = f2bf(v.z); o.w = f2bf(v.w);
    } else {
        o.x = 0; o.y = 0; o.z = 0; o.w = 0;
    }
    *(ushort4*)(Xb + i) = o;
}

// ---- Kernel 1b: W [4][1280][256] fp32 -> WbT bf16 [n=k*256+h][d] (B^T layout) ----
__global__ void cvtW_kernel(const float* __restrict__ W, ushort* __restrict__ WbT) {
    int o = blockIdx.x * 256 + threadIdx.x;
    if (o >= NTOT * D_IN) return;
    int n = o / D_IN, d = o - n * D_IN;
    int k = n >> 8, h = n & 255;
    WbT[o] = f2bf(W[(k * D_IN + d) * H_OUT + h]);
}

// ---- Kernel 2: single-pass bucket scatter.  edge record = (Yb offset, val) ----
__global__ void scatter_kernel(const int* __restrict__ rows, const int* __restrict__ cols,
                               const float* __restrict__ vals, int* __restrict__ cnt,
                               int2* __restrict__ edges) {
    int i = blockIdx.x * 256 + threadIdx.x;
    if (i >= K1H * E_EDGES) return;
    int k = i / E_EDGES;                     // hop index 0..3
    int r = rows[i];
    int pos = atomicAdd(&cnt[r], 1);
    if (pos < CAP)                           // statistically never taken
        edges[(size_t)r * CAP + pos] =
            make_int2((cols[i] << 10) | (k << 8), __float_as_int(vals[i]));
}

// ---- Kernel 3: GEMM  Yb[MP,1024] = Xb[MP,1280] @ WbT^T  (bf16 MFMA, bf16 out) ----
// Round-2 proven schedule (8 phases / 2 K-tiles, one barrier per phase, counted
// vmcnt with >=2-phase load-issue->consume distance), now templated on tile
// height: MTF=4 -> BM=256 (full), MTF=2 -> BM=128 (half).  Heterogeneous grid
// (704 fulls then 160 halves) packs the 3.0625-round workload into ~3.5 rounds
// instead of 4: halves fill the slots the last full-round leaves idle.
// vmcnt constants re-derived parametrically (alpha = A-stage instrs = MTF/2,
// beta = 2): main ph1/ph5 = 2a+2, ph4/ph8 = 2a+4, prologue = 2a+4,
// tail ph1 = 2a+2, ph4 = a+2, ph5 = 0.  Queue invariant verified to close.
#define BARR() __builtin_amdgcn_s_barrier()
#define LGKM0() { asm volatile("s_waitcnt lgkmcnt(0)" ::: "memory"); \
                  __builtin_amdgcn_sched_barrier(0); }

template<int N> __device__ __forceinline__ void vmc() {
    if constexpr (N == 0)      asm volatile("s_waitcnt vmcnt(0)" ::: "memory");
    else if constexpr (N == 3) asm volatile("s_waitcnt vmcnt(3)" ::: "memory");
    else if constexpr (N == 4) asm volatile("s_waitcnt vmcnt(4)" ::: "memory");
    else if constexpr (N == 6) asm volatile("s_waitcnt vmcnt(6)" ::: "memory");
    else if constexpr (N == 8) asm volatile("s_waitcnt vmcnt(8)" ::: "memory");
    else static_assert(N == 0, "unsupported vmcnt");
}

#define lA(BUF) (lds0 + ((BUF) * 2 + 0) * 16384)
#define lB(BUF) (lds0 + ((BUF) * 2 + 1) * 16384)

#define STAGE_A(BUF, G, KT) { \
    if constexpr (MTF == 4) { \
        _Pragma("unroll") for (int r = 0; r < 2; ++r) \
            g2lds16(pA + ((r) * 128 + (G) * 64) * D_IN + (KT) * 64, \
                    lA(BUF) + (t + (G) * 512 + (r) * 1024) * 8); \
    } else { \
        const int r64 = t >> 3, hi = (t >> 8) & 1; \
        g2lds16(pA + ((G) * 32 + hi * 32) * D_IN + (KT) * 64, \
                lA(BUF) + (((G) * 32 + (r64 & 31) + hi * 64) * 8 + (t & 7)) * 8); \
    } }
#define STAGE_B(BUF, G, KT) { _Pragma("unroll") \
    for (int r = 0; r < 2; ++r) \
        g2lds16(pB + ((r) * 128 + (G) * 32) * D_IN + (KT) * 64, \
                lB(BUF) + (t + wm * 256 + (G) * 256 + (r) * 1024) * 8); }
#define LDA_F(BUF, MH) { _Pragma("unroll") \
    for (int mt = 0; mt < MTF; ++mt) { \
        const int m = wm * (MTF * 32) + (MH) * (MTF * 16) + mt * 16 + l16; \
        _Pragma("unroll") for (int ks = 0; ks < 2; ++ks) \
            af[mt][ks] = *(const s16x8*)(lA(BUF) + (m * 8 + ((ks * 4 + quad) ^ (l16 & 7))) * 8); } }
#define LDB_F(BUF, NH) { _Pragma("unroll") \
    for (int nt = 0; nt < 2; ++nt) { \
        const int n = wn * 64 + (NH) * 32 + nt * 16 + l16; \
        _Pragma("unroll") for (int ks = 0; ks < 2; ++ks) \
            bfr[NH][nt][ks] = *(const s16x8*)(lB(BUF) + (n * 8 + ((ks * 4 + quad) ^ (l16 & 7))) * 8); } }
#define MMA_Q(MH, NH) { __builtin_amdgcn_s_setprio(1); \
    _Pragma("unroll") for (int mt = 0; mt < MTF; ++mt) \
        _Pragma("unroll") for (int nt = 0; nt < 2; ++nt) \
            _Pragma("unroll") for (int ks = 0; ks < 2; ++ks) \
                acc[(MH) * MTF + mt][(NH) * 2 + nt] = \
                    __builtin_amdgcn_mfma_f32_16x16x32_bf16(af[mt][ks], bfr[NH][nt][ks], \
                        acc[(MH) * MTF + mt][(NH) * 2 + nt], 0, 0, 0); \
    __builtin_amdgcn_s_setprio(0); }

template<int MTF>
__device__ __forceinline__ void gemm_body(ushort* lds0,
        const ushort* __restrict__ Xb, const ushort* __restrict__ WbT,
        ushort* __restrict__ Yb, const int rowBase, const int colBase, const int t) {
    constexpr int AL = MTF / 2;            // A-stage gload instrs per unit
    constexpr int VA = 2 * AL + 2;         // main ph1, ph5; tail ph1
    constexpr int VB = 2 * AL + 4;         // main ph4, ph8; prologue
    constexpr int VT = AL + 2;             // tail ph4

    const int w = t >> 6, lane = t & 63;
    const int quad = lane >> 4, l16 = lane & 15;
    const int wm = w >> 2, wn = w & 3;     // 2 x 4 wave grid

    f32x4 acc[MTF * 2][4] = {};
    s16x8 af[MTF][2];
    s16x8 bfr[2][2][2];

    const int kcg = (t & 7) ^ ((t >> 3) & 7);
    const ushort* pA = Xb + (rowBase + (t >> 3)) * D_IN + kcg * 8;
    const ushort* pB = WbT + (colBase + (t >> 3) + wm * 32) * D_IN + kcg * 8;

    // prologue: tile0 (4 units -> buf0) + tile1 Ag0,Bg0 (-> buf1)
    STAGE_A(0, 0, 0); STAGE_B(0, 0, 0); STAGE_A(0, 1, 0); STAGE_B(0, 1, 0);
    STAGE_A(1, 0, 1); STAGE_B(1, 0, 1);
    vmc<VB>();
    BARR();

#pragma unroll 1
    for (int i = 0; i < 9; ++i) {
        const int kt0 = 2 * i;
        LDA_F(0, 0); LDB_F(0, 0); STAGE_A(1, 1, kt0 + 1); vmc<VA>();   // ph1
        BARR(); LGKM0(); MMA_Q(0, 0);
        LDB_F(0, 1); STAGE_B(1, 1, kt0 + 1);                           // ph2
        BARR(); LGKM0(); MMA_Q(0, 1);
        LDA_F(0, 1); STAGE_A(0, 0, kt0 + 2);                           // ph3
        BARR(); LGKM0(); MMA_Q(1, 0);
        STAGE_B(0, 0, kt0 + 2); vmc<VB>();                             // ph4
        BARR(); MMA_Q(1, 1);
        LDA_F(1, 0); LDB_F(1, 0); STAGE_A(0, 1, kt0 + 2); vmc<VA>();   // ph5
        BARR(); LGKM0(); MMA_Q(0, 0);
        LDB_F(1, 1); STAGE_B(0, 1, kt0 + 2);                           // ph6
        BARR(); LGKM0(); MMA_Q(0, 1);
        LDA_F(1, 1); STAGE_A(1, 0, kt0 + 3);                           // ph7
        BARR(); LGKM0(); MMA_Q(1, 0);
        STAGE_B(1, 0, kt0 + 3); vmc<VB>();                             // ph8
        BARR(); MMA_Q(1, 1);
    }

    // tail: tiles 18 (buf0) and 19 (buf1); only t19.Ag1/Bg1 still need staging.
    LDA_F(0, 0); LDB_F(0, 0); STAGE_A(1, 1, 19); vmc<VA>();            // ph1
    BARR(); LGKM0(); MMA_Q(0, 0);
    LDB_F(0, 1); STAGE_B(1, 1, 19);                                    // ph2
    BARR(); LGKM0(); MMA_Q(0, 1);
    LDA_F(0, 1);                                                       // ph3
    BARR(); LGKM0(); MMA_Q(1, 0);
    vmc<VT>();                                                         // ph4
    BARR(); MMA_Q(1, 1);
    LDA_F(1, 0); LDB_F(1, 0); vmc<0>();                                // ph5
    BARR(); LGKM0(); MMA_Q(0, 0);
    LDB_F(1, 1);                                                       // ph6
    BARR(); LGKM0(); MMA_Q(0, 1);
    LDA_F(1, 1);                                                       // ph7
    BARR(); LGKM0(); MMA_Q(1, 0);
    MMA_Q(1, 1);                                                       // ph8

    // C/D layout: col = lane&15, row = quad*4 + reg  (m89/m91 verified)
    #pragma unroll
    for (int mh = 0; mh < 2; ++mh)
      #pragma unroll
      for (int mt = 0; mt < MTF; ++mt)
        #pragma unroll
        for (int nh = 0; nh < 2; ++nh)
          #pragma unroll
          for (int nt = 0; nt < 2; ++nt) {
            const int rr = rowBase + wm * (MTF * 32) + mh * (MTF * 16) + mt * 16 + quad * 4;
            const int cc = colBase + wn * 64 + nh * 32 + nt * 16 + l16;
            #pragma unroll
            for (int r = 0; r < 4; ++r)
                Yb[(rr + r) * NTOT + cc] = f2bf(acc[mh * MTF + mt][nh * 2 + nt][r]);
          }
}

__global__ void __launch_bounds__(512, 2)
gemm_kernel(const ushort* __restrict__ Xb, const ushort* __restrict__ WbT,
            ushort* __restrict__ Yb) {
    __shared__ ushort lds[2][2][256 * 64];   // 128 KiB (halves use half of A regions)
    const int bid = blockIdx.x;
    const int t = threadIdx.x;
    if (bid < NFULL) {                        // full tiles first: fill rounds 1-3
        const int xcd = bid & 7, j = bid >> 3;      // 88 blocks per XCD
        const int j2 = xcd * 88 + j;
        gemm_body<4>(&lds[0][0][0], Xb, WbT, Yb, (j2 >> 2) * 256, (j2 & 3) * 256, t);
    } else {                                  // half tiles drain into idle slots
        const int hb = bid - NFULL;
        const int j2 = (hb & 7) * 20 + (hb >> 3);   // 20 per XCD
        gemm_body<2>(&lds[0][0][0], Xb, WbT, Yb,
                     HALF_BASE + (j2 >> 2) * 128, (j2 & 3) * 256, t);
    }
}

#undef STAGE_A
#undef STAGE_B
#undef LDA_F
#undef LDB_F
#undef MMA_Q
#undef lA
#undef lB

// ---- Kernel 4: bucket gather-SpMM + bias + PReLU.  One WAVE per dest row ----
// Lane l holds h = l*4 .. l*4+3; per edge one coalesced 512B ushort4 slice load.
__global__ void __launch_bounds__(256)
spmm_kernel(const int2* __restrict__ edges, const int* __restrict__ cnt,
            const ushort* __restrict__ Yb, const float* __restrict__ b,
            const float* __restrict__ alpha, float* __restrict__ out) {
    const int wid = threadIdx.x >> 6, lane = threadIdx.x & 63;
    const int row = blockIdx.x * 4 + wid;          // N_NODES = 12500 * 4 exactly
    const int h0 = lane * 4;

    float4 acc = make_float4(0.f, 0.f, 0.f, 0.f);
    #pragma unroll
    for (int k = 0; k < K1H; ++k) {
        const float4 bb = *(const float4*)(b + k * H_OUT + h0);
        acc.x += bb.x; acc.y += bb.y; acc.z += bb.z; acc.w += bb.w;
    }

    const int2* eb = edges + (size_t)row * CAP;
    int e = cnt[row]; if (e > CAP) e = CAP;
    int j = 0;
    for (; j + 4 <= e; j += 4) {                   // 4 gather streams in flight
        const int2 e0 = eb[j], e1 = eb[j + 1], e2 = eb[j + 2], e3 = eb[j + 3];
        const ushort4 y0 = *(const ushort4*)(Yb + e0.x + h0);
        const ushort4 y1 = *(const ushort4*)(Yb + e1.x + h0);
        const ushort4 y2 = *(const ushort4*)(Yb + e2.x + h0);
        const ushort4 y3 = *(const ushort4*)(Yb + e3.x + h0);
        const float v0 = __int_as_float(e0.y), v1 = __int_as_float(e1.y);
        const float v2 = __int_as_float(e2.y), v3 = __int_as_float(e3.y);
        acc.x += v0 * bf2f(y0.x) + v1 * bf2f(y1.x) + v2 * bf2f(y2.x) + v3 * bf2f(y3.x);
        acc.y += v0 * bf2f(y0.y) + v1 * bf2f(y1.y) + v2 * bf2f(y2.y) + v3 * bf2f(y3.y);
        acc.z += v0 * bf2f(y0.z) + v1 * bf2f(y1.z) + v2 * bf2f(y2.z) + v3 * bf2f(y3.z);
        acc.w += v0 * bf2f(y0.w) + v1 * bf2f(y1.w) + v2 * bf2f(y2.w) + v3 * bf2f(y3.w);
    }
    for (; j < e; ++j) {
        const int2 ed = eb[j];
        const float v = __int_as_float(ed.y);
        const ushort4 y = *(const ushort4*)(Yb + ed.x + h0);
        acc.x += v * bf2f(y.x);
        acc.y += v * bf2f(y.y);
        acc.z += v * bf2f(y.z);
        acc.w += v * bf2f(y.w);
    }

    const float a = alpha[0];
    float4 o;
    o.x = acc.x >= 0.f ? acc.x : a * acc.x;
    o.y = acc.y >= 0.f ? acc.y : a * acc.y;
    o.z = acc.z >= 0.f ? acc.z : a * acc.z;
    o.w = acc.w >= 0.f ? acc.w : a * acc.w;
    *(float4*)(out + row * H_OUT + h0) = o;
}

static inline size_t align256(size_t x) { return (x + 255) & ~(size_t)255; }

extern "C" void kernel_launch(void* const* d_in, const int* in_sizes, int n_in,
                              void* d_out, int out_size, void* d_ws, size_t ws_size,
                              hipStream_t stream) {
    const float* X     = (const float*)d_in[0];
    const int*   rows  = (const int*)d_in[1];
    const int*   cols  = (const int*)d_in[2];
    const float* vals  = (const float*)d_in[3];
    const float* W     = (const float*)d_in[4];
    const float* b     = (const float*)d_in[5];
    const float* alpha = (const float*)d_in[6];
    float* out = (float*)d_out;

    char* ws = (char*)d_ws;
    size_t off = 0;
    ushort* Xb  = (ushort*)(ws + off); off = align256(off + (size_t)MP * D_IN * 2);
    ushort* WbT = (ushort*)(ws + off); off = align256(off + (size_t)NTOT * D_IN * 2);
    ushort* Yb  = (ushort*)(ws + off); off = align256(off + (size_t)MP * NTOT * 2);
    int* cnt    = (int*)(ws + off);    off = align256(off + (size_t)N_NODES * 4);
    int2* edges = (int2*)(ws + off);   off = align256(off + (size_t)N_NODES * CAP * 8);

    hipMemsetAsync(cnt, 0, (size_t)N_NODES * 4, stream);

    cvtX_kernel<<<MP * D_IN / 4 / 256, 256, 0, stream>>>(X, Xb);
    cvtW_kernel<<<(NTOT * D_IN + 255) / 256, 256, 0, stream>>>(W, WbT);
    scatter_kernel<<<(K1H * E_EDGES + 255) / 256, 256, 0, stream>>>(rows, cols, vals, cnt, edges);
    gemm_kernel<<<NFULL + NHALF, 512, 0, stream>>>(Xb, WbT, Yb);
    spmm_kernel<<<N_NODES / 4, 256, 0, stream>>>(edges, cnt, Yb, b, alpha, out);
}

// Round 5
// 727.885 us; speedup vs baseline: 1.0527x; 1.0091x over previous
//
#include <hip/hip_runtime.h>
#include <hip/hip_bf16.h>
#include <stdint.h>

#define N_NODES 50000
#define E_EDGES 400000
#define K1H 4
#define D_IN 1280
#define H_OUT 256
#define NTOT 1024          // K1H * H_OUT (fused GEMM output width)
#define MP 50176           // N padded: 176 row-tiles of 256 + 40 row-tiles of 128
#define NFULL 704          // 176 full row-tiles * 4 col-tiles
#define NHALF 160          // 40 half row-tiles * 4 col-tiles
#define HALF_BASE 45056    // first row of the half-tile region (176*256)
#define CAP 128            // edge bucket capacity per dest row (lambda=32, overflow ~e^-60)

// prep_kernel grid partition (scatter first so its atomic-latency phase
// co-resides with cvtX's BW streaming)
#define NB_BSUM 1
#define NB_SCAT 6250       // 1,600,000 / 256
#define NB_CVTW 5120       // 1,310,720 / 256
#define NB_CVTX 62720      // MP*D_IN/4/256

typedef float f32x4 __attribute__((ext_vector_type(4)));
typedef short s16x8 __attribute__((ext_vector_type(8)));

#define GLOBAL_AS __attribute__((address_space(1)))
#define LDS_AS __attribute__((address_space(3)))

__device__ __forceinline__ void g2lds16(const void* g, void* l) {
    __builtin_amdgcn_global_load_lds((const GLOBAL_AS uint32_t*)g,
                                     (LDS_AS uint32_t*)l, 16, 0, 0);
}

// fp32 -> bf16 round-nearest-even
__device__ __forceinline__ ushort f2bf(float x) {
    uint32_t u = __float_as_uint(x);
    uint32_t r = u + 0x7FFFu + ((u >> 16) & 1u);
    return (ushort)(r >> 16);
}
__device__ __forceinline__ float bf2f(ushort u) {
    return __uint_as_float(((uint32_t)u) << 16);
}

// ---- Kernel 1: fused prep.  Partition of one grid:
//   blk 0                 : bsum[h] = sum_k b[k][h]            (for spmm)
//   blk [1, 1+NB_SCAT)    : edge bucket scatter (atomic-latency bound)
//   next NB_CVTW          : W fp32 -> WbT bf16 [n][d] (B^T layout)
//   next NB_CVTX          : X fp32 [N,D] -> Xb bf16 [MP,D], pad rows zeroed
// Scatter+cvtW overlap with cvtX instead of serializing as 3 launches.
__global__ void __launch_bounds__(256)
prep_kernel(const float* __restrict__ X, ushort* __restrict__ Xb,
            const float* __restrict__ W, ushort* __restrict__ WbT,
            const int* __restrict__ rows, const int* __restrict__ cols,
            const float* __restrict__ vals, int* __restrict__ cnt,
            int2* __restrict__ edges, const float* __restrict__ b,
            float* __restrict__ bsum) {
    const int blk = blockIdx.x, tid = threadIdx.x;
    if (blk == 0) {
        bsum[tid] = b[tid] + b[256 + tid] + b[512 + tid] + b[768 + tid];
    } else if (blk < NB_BSUM + NB_SCAT) {
        const int i = (blk - NB_BSUM) * 256 + tid;        // < 1.6M exactly
        const int k = i / E_EDGES;                        // hop index 0..3
        const int r = rows[i];
        const int pos = atomicAdd(&cnt[r], 1);
        if (pos < CAP)                                    // statistically never taken
            edges[(size_t)r * CAP + pos] =
                make_int2((cols[i] << 10) | (k << 8), __float_as_int(vals[i]));
    } else if (blk < NB_BSUM + NB_SCAT + NB_CVTW) {
        const int o = (blk - NB_BSUM - NB_SCAT) * 256 + tid;   // < NTOT*D_IN exactly
        const int n = o / D_IN, d = o - n * D_IN;
        const int k = n >> 8, h = n & 255;
        WbT[o] = f2bf(W[(k * D_IN + d) * H_OUT + h]);
    } else {
        const int i = ((blk - NB_BSUM - NB_SCAT - NB_CVTW) * 256 + tid) * 4;
        ushort4 o4;
        if (i < N_NODES * D_IN) {
            const float4 v = *(const float4*)(X + i);
            o4.x = f2bf(v.x); o4.y = f2bf(v.y); o4.z = f2bf(v.z); o4.w = f2bf(v.w);
        } else {
            o4.x = 0; o4.y = 0; o4.z = 0; o4.w = 0;
        }
        *(ushort4*)(Xb + i) = o4;
    }
}

// ---- Kernel 2: GEMM  Yb[MP,1024] = Xb[MP,1280] @ WbT^T  (bf16 MFMA, bf16 out) ----
// Round-2 proven schedule (8 phases / 2 K-tiles, one barrier per phase, counted
// vmcnt with >=2-phase load-issue->consume distance), templated on tile height:
// MTF=4 -> BM=256 (full), MTF=2 -> BM=128 (half).  Heterogeneous grid (704
// fulls then 160 halves) packs the 3.0625-round workload into 3.5 rounds.
#define BARR() __builtin_amdgcn_s_barrier()
#define LGKM0() { asm volatile("s_waitcnt lgkmcnt(0)" ::: "memory"); \
                  __builtin_amdgcn_sched_barrier(0); }

template<int N> __device__ __forceinline__ void vmc() {
    if constexpr (N == 0)      asm volatile("s_waitcnt vmcnt(0)" ::: "memory");
    else if constexpr (N == 3) asm volatile("s_waitcnt vmcnt(3)" ::: "memory");
    else if constexpr (N == 4) asm volatile("s_waitcnt vmcnt(4)" ::: "memory");
    else if constexpr (N == 6) asm volatile("s_waitcnt vmcnt(6)" ::: "memory");
    else if constexpr (N == 8) asm volatile("s_waitcnt vmcnt(8)" ::: "memory");
    else static_assert(N == 0, "unsupported vmcnt");
}

#define lA(BUF) (lds0 + ((BUF) * 2 + 0) * 16384)
#define lB(BUF) (lds0 + ((BUF) * 2 + 1) * 16384)

#define STAGE_A(BUF, G, KT) { \
    if constexpr (MTF == 4) { \
        _Pragma("unroll") for (int r = 0; r < 2; ++r) \
            g2lds16(pA + ((r) * 128 + (G) * 64) * D_IN + (KT) * 64, \
                    lA(BUF) + (t + (G) * 512 + (r) * 1024) * 8); \
    } else { \
        const int r64 = t >> 3, hi = (t >> 8) & 1; \
        g2lds16(pA + ((G) * 32 + hi * 32) * D_IN + (KT) * 64, \
                lA(BUF) + (((G) * 32 + (r64 & 31) + hi * 64) * 8 + (t & 7)) * 8); \
    } }
#define STAGE_B(BUF, G, KT) { _Pragma("unroll") \
    for (int r = 0; r < 2; ++r) \
        g2lds16(pB + ((r) * 128 + (G) * 32) * D_IN + (KT) * 64, \
                lB(BUF) + (t + wm * 256 + (G) * 256 + (r) * 1024) * 8); }
#define LDA_F(BUF, MH) { _Pragma("unroll") \
    for (int mt = 0; mt < MTF; ++mt) { \
        const int m = wm * (MTF * 32) + (MH) * (MTF * 16) + mt * 16 + l16; \
        _Pragma("unroll") for (int ks = 0; ks < 2; ++ks) \
            af[mt][ks] = *(const s16x8*)(lA(BUF) + (m * 8 + ((ks * 4 + quad) ^ (l16 & 7))) * 8); } }
#define LDB_F(BUF, NH) { _Pragma("unroll") \
    for (int nt = 0; nt < 2; ++nt) { \
        const int n = wn * 64 + (NH) * 32 + nt * 16 + l16; \
        _Pragma("unroll") for (int ks = 0; ks < 2; ++ks) \
            bfr[NH][nt][ks] = *(const s16x8*)(lB(BUF) + (n * 8 + ((ks * 4 + quad) ^ (l16 & 7))) * 8); } }
#define MMA_Q(MH, NH) { __builtin_amdgcn_s_setprio(1); \
    _Pragma("unroll") for (int mt = 0; mt < MTF; ++mt) \
        _Pragma("unroll") for (int nt = 0; nt < 2; ++nt) \
            _Pragma("unroll") for (int ks = 0; ks < 2; ++ks) \
                acc[(MH) * MTF + mt][(NH) * 2 + nt] = \
                    __builtin_amdgcn_mfma_f32_16x16x32_bf16(af[mt][ks], bfr[NH][nt][ks], \
                        acc[(MH) * MTF + mt][(NH) * 2 + nt], 0, 0, 0); \
    __builtin_amdgcn_s_setprio(0); }

template<int MTF>
__device__ __forceinline__ void gemm_body(ushort* lds0,
        const ushort* __restrict__ Xb, const ushort* __restrict__ WbT,
        ushort* __restrict__ Yb, const int rowBase, const int colBase, const int t) {
    constexpr int AL = MTF / 2;            // A-stage gload instrs per unit
    constexpr int VA = 2 * AL + 2;         // main ph1, ph5; tail ph1
    constexpr int VB = 2 * AL + 4;         // main ph4, ph8; prologue
    constexpr int VT = AL + 2;             // tail ph4

    const int w = t >> 6, lane = t & 63;
    const int quad = lane >> 4, l16 = lane & 15;
    const int wm = w >> 2, wn = w & 3;     // 2 x 4 wave grid

    f32x4 acc[MTF * 2][4] = {};
    s16x8 af[MTF][2];
    s16x8 bfr[2][2][2];

    const int kcg = (t & 7) ^ ((t >> 3) & 7);
    const ushort* pA = Xb + (rowBase + (t >> 3)) * D_IN + kcg * 8;
    const ushort* pB = WbT + (colBase + (t >> 3) + wm * 32) * D_IN + kcg * 8;

    // prologue: tile0 (4 units -> buf0) + tile1 Ag0,Bg0 (-> buf1)
    STAGE_A(0, 0, 0); STAGE_B(0, 0, 0); STAGE_A(0, 1, 0); STAGE_B(0, 1, 0);
    STAGE_A(1, 0, 1); STAGE_B(1, 0, 1);
    vmc<VB>();
    BARR();

#pragma unroll 1
    for (int i = 0; i < 9; ++i) {
        const int kt0 = 2 * i;
        LDA_F(0, 0); LDB_F(0, 0); STAGE_A(1, 1, kt0 + 1); vmc<VA>();   // ph1
        BARR(); LGKM0(); MMA_Q(0, 0);
        LDB_F(0, 1); STAGE_B(1, 1, kt0 + 1);                           // ph2
        BARR(); LGKM0(); MMA_Q(0, 1);
        LDA_F(0, 1); STAGE_A(0, 0, kt0 + 2);                           // ph3
        BARR(); LGKM0(); MMA_Q(1, 0);
        STAGE_B(0, 0, kt0 + 2); vmc<VB>();                             // ph4
        BARR(); MMA_Q(1, 1);
        LDA_F(1, 0); LDB_F(1, 0); STAGE_A(0, 1, kt0 + 2); vmc<VA>();   // ph5
        BARR(); LGKM0(); MMA_Q(0, 0);
        LDB_F(1, 1); STAGE_B(0, 1, kt0 + 2);                           // ph6
        BARR(); LGKM0(); MMA_Q(0, 1);
        LDA_F(1, 1); STAGE_A(1, 0, kt0 + 3);                           // ph7
        BARR(); LGKM0(); MMA_Q(1, 0);
        STAGE_B(1, 0, kt0 + 3); vmc<VB>();                             // ph8
        BARR(); MMA_Q(1, 1);
    }

    // tail: tiles 18 (buf0) and 19 (buf1); only t19.Ag1/Bg1 still need staging.
    LDA_F(0, 0); LDB_F(0, 0); STAGE_A(1, 1, 19); vmc<VA>();            // ph1
    BARR(); LGKM0(); MMA_Q(0, 0);
    LDB_F(0, 1); STAGE_B(1, 1, 19);                                    // ph2
    BARR(); LGKM0(); MMA_Q(0, 1);
    LDA_F(0, 1);                                                       // ph3
    BARR(); LGKM0(); MMA_Q(1, 0);
    vmc<VT>();                                                         // ph4
    BARR(); MMA_Q(1, 1);
    LDA_F(1, 0); LDB_F(1, 0); vmc<0>();                                // ph5
    BARR(); LGKM0(); MMA_Q(0, 0);
    LDB_F(1, 1);                                                       // ph6
    BARR(); LGKM0(); MMA_Q(0, 1);
    LDA_F(1, 1);                                                       // ph7
    BARR(); LGKM0(); MMA_Q(1, 0);
    MMA_Q(1, 1);                                                       // ph8

    // C/D layout: col = lane&15, row = quad*4 + reg  (m89/m91 verified)
    #pragma unroll
    for (int mh = 0; mh < 2; ++mh)
      #pragma unroll
      for (int mt = 0; mt < MTF; ++mt)
        #pragma unroll
        for (int nh = 0; nh < 2; ++nh)
          #pragma unroll
          for (int nt = 0; nt < 2; ++nt) {
            const int rr = rowBase + wm * (MTF * 32) + mh * (MTF * 16) + mt * 16 + quad * 4;
            const int cc = colBase + wn * 64 + nh * 32 + nt * 16 + l16;
            #pragma unroll
            for (int r = 0; r < 4; ++r)
                Yb[(rr + r) * NTOT + cc] = f2bf(acc[mh * MTF + mt][nh * 2 + nt][r]);
          }
}

__global__ void __launch_bounds__(512, 2)
gemm_kernel(const ushort* __restrict__ Xb, const ushort* __restrict__ WbT,
            ushort* __restrict__ Yb) {
    __shared__ ushort lds[2][2][256 * 64];   // 128 KiB (halves use half of A regions)
    const int bid = blockIdx.x;
    const int t = threadIdx.x;
    if (bid < NFULL) {                        // full tiles first: fill rounds 1-3
        const int xcd = bid & 7, j = bid >> 3;      // 88 blocks per XCD
        const int j2 = xcd * 88 + j;
        gemm_body<4>(&lds[0][0][0], Xb, WbT, Yb, (j2 >> 2) * 256, (j2 & 3) * 256, t);
    } else {                                  // half tiles drain into idle slots
        const int hb = bid - NFULL;
        const int j2 = (hb & 7) * 20 + (hb >> 3);   // 20 per XCD
        gemm_body<2>(&lds[0][0][0], Xb, WbT, Yb,
                     HALF_BASE + (j2 >> 2) * 128, (j2 & 3) * 256, t);
    }
}

#undef STAGE_A
#undef STAGE_B
#undef LDA_F
#undef LDB_F
#undef MMA_Q
#undef lA
#undef lB

// ---- Kernel 3: bucket gather-SpMM + bias + PReLU.  One WAVE per dest row ----
// Lane l holds h = l*4 .. l*4+3; per edge one coalesced 512B ushort4 slice load.
// 8 gather streams in flight (static-indexed, fully unrolled); bias presummed.
__global__ void __launch_bounds__(256)
spmm_kernel(const int2* __restrict__ edges, const int* __restrict__ cnt,
            const ushort* __restrict__ Yb, const float* __restrict__ bsum,
            const float* __restrict__ alpha, float* __restrict__ out) {
    const int wid = threadIdx.x >> 6, lane = threadIdx.x & 63;
    const int row = blockIdx.x * 4 + wid;          // N_NODES = 12500 * 4 exactly
    const int h0 = lane * 4;

    const float4 bb = *(const float4*)(bsum + h0);
    float4 acc = bb;

    const int2* eb = edges + (size_t)row * CAP;
    int e = cnt[row]; if (e > CAP) e = CAP;
    int j = 0;
    for (; j + 8 <= e; j += 8) {                   // 8 gather streams in flight
        int2 er[8]; ushort4 y[8]; float v[8];
        #pragma unroll
        for (int s = 0; s < 8; ++s) er[s] = eb[j + s];
        #pragma unroll
        for (int s = 0; s < 8; ++s) y[s] = *(const ushort4*)(Yb + er[s].x + h0);
        #pragma unroll
        for (int s = 0; s < 8; ++s) v[s] = __int_as_float(er[s].y);
        #pragma unroll
        for (int s = 0; s < 8; ++s) {
            acc.x += v[s] * bf2f(y[s].x);
            acc.y += v[s] * bf2f(y[s].y);
            acc.z += v[s] * bf2f(y[s].z);
            acc.w += v[s] * bf2f(y[s].w);
        }
    }
    for (; j < e; ++j) {
        const int2 ed = eb[j];
        const float v = __int_as_float(ed.y);
        const ushort4 y = *(const ushort4*)(Yb + ed.x + h0);
        acc.x += v * bf2f(y.x);
        acc.y += v * bf2f(y.y);
        acc.z += v * bf2f(y.z);
        acc.w += v * bf2f(y.w);
    }

    const float a = alpha[0];
    float4 o;
    o.x = acc.x >= 0.f ? acc.x : a * acc.x;
    o.y = acc.y >= 0.f ? acc.y : a * acc.y;
    o.z = acc.z >= 0.f ? acc.z : a * acc.z;
    o.w = acc.w >= 0.f ? acc.w : a * acc.w;
    *(float4*)(out + row * H_OUT + h0) = o;
}

static inline size_t align256(size_t x) { return (x + 255) & ~(size_t)255; }

extern "C" void kernel_launch(void* const* d_in, const int* in_sizes, int n_in,
                              void* d_out, int out_size, void* d_ws, size_t ws_size,
                              hipStream_t stream) {
    const float* X     = (const float*)d_in[0];
    const int*   rows  = (const int*)d_in[1];
    const int*   cols  = (const int*)d_in[2];
    const float* vals  = (const float*)d_in[3];
    const float* W     = (const float*)d_in[4];
    const float* b     = (const float*)d_in[5];
    const float* alpha = (const float*)d_in[6];
    float* out = (float*)d_out;

    char* ws = (char*)d_ws;
    size_t off = 0;
    ushort* Xb  = (ushort*)(ws + off); off = align256(off + (size_t)MP * D_IN * 2);
    ushort* WbT = (ushort*)(ws + off); off = align256(off + (size_t)NTOT * D_IN * 2);
    ushort* Yb  = (ushort*)(ws + off); off = align256(off + (size_t)MP * NTOT * 2);
    int* cnt    = (int*)(ws + off);    off = align256(off + (size_t)N_NODES * 4);
    int2* edges = (int2*)(ws + off);   off = align256(off + (size_t)N_NODES * CAP * 8);
    float* bsum = (float*)(ws + off);  off = align256(off + (size_t)H_OUT * 4);

    hipMemsetAsync(cnt, 0, (size_t)N_NODES * 4, stream);

    prep_kernel<<<NB_BSUM + NB_SCAT + NB_CVTW + NB_CVTX, 256, 0, stream>>>(
        X, Xb, W, WbT, rows, cols, vals, cnt, edges, b, bsum);
    gemm_kernel<<<NFULL + NHALF, 512, 0, stream>>>(Xb, WbT, Yb);
    spmm_kernel<<<N_NODES / 4, 256, 0, stream>>>(edges, cnt, Yb, bsum, alpha, out);
}